// Round 5
// baseline (1200.341 us; speedup 1.0000x reference)
//
#include <hip/hip_runtime.h>

typedef short bf16x8 __attribute__((ext_vector_type(8)));
typedef float f32x4  __attribute__((ext_vector_type(4)));
typedef int   i32x4  __attribute__((ext_vector_type(4)));
typedef unsigned int u32x4 __attribute__((ext_vector_type(4)));

__device__ __forceinline__ unsigned short f32_to_bf16(float f) {
  union { float f; unsigned int u; } v; v.f = f;
  unsigned int u = v.u;
  u += 0x7fffu + ((u >> 16) & 1u);   // round-to-nearest-even
  return (unsigned short)(u >> 16);
}
__device__ __forceinline__ float bf16lo_to_f32(unsigned int u) {
  union { unsigned int u; float f; } v; v.u = u << 16; return v.f;
}
__device__ __forceinline__ float bf16hi_to_f32(unsigned int u) {
  union { unsigned int u; float f; } v; v.u = u & 0xffff0000u; return v.f;
}

// h = x @ W.T + b, h[0,:] = 0, stored as bf16.
// sliced=1: h_s[s][row][32] layout (s = col>>5) for the XCD-sliced gather.
// sliced=0: row-major h[row][256].
__global__ __launch_bounds__(256, 2) void gin_gemm(
    const float* __restrict__ x, const float* __restrict__ W,
    const float* __restrict__ bias, unsigned short* __restrict__ h, int M,
    int sliced) {
  __shared__ __align__(16) unsigned short As[64 * 32];   // [row][k]  4 KB
  __shared__ __align__(16) unsigned short Bs[256 * 32];  // [col][k] 16 KB

  const int tid  = threadIdx.x;
  const int wid  = tid >> 6;
  const int lane = tid & 63;
  const int row0 = blockIdx.x * 64;

  f32x4 acc[4][4] = {};  // [row-group][col-group], 64 VGPRs

  // staging mapping: thread covers 8 contiguous k's of one row
  const int srow = tid >> 2;          // 0..63
  const int sk0  = (tid & 3) << 3;    // 0,8,16,24
  int agrow = row0 + srow;
  if (agrow >= M) agrow = M - 1;      // clamp; results discarded in epilogue
  const float* aRow = x + (size_t)agrow * 256 + sk0;
  const float* bRow = W + (size_t)srow * 256 + sk0;

  for (int kt = 0; kt < 8; ++kt) {
    const int kb = kt * 32;
    // stage A: 64x32 f32 -> bf16
    {
      float4 v0 = *(const float4*)(aRow + kb);
      float4 v1 = *(const float4*)(aRow + kb + 4);
      bf16x8 u;
      u[0] = (short)f32_to_bf16(v0.x); u[1] = (short)f32_to_bf16(v0.y);
      u[2] = (short)f32_to_bf16(v0.z); u[3] = (short)f32_to_bf16(v0.w);
      u[4] = (short)f32_to_bf16(v1.x); u[5] = (short)f32_to_bf16(v1.y);
      u[6] = (short)f32_to_bf16(v1.z); u[7] = (short)f32_to_bf16(v1.w);
      *(bf16x8*)(&As[srow * 32 + sk0]) = u;
    }
    // stage B: 256x32 (W rows = output cols)
#pragma unroll
    for (int j = 0; j < 4; ++j) {
      const float* p = bRow + (size_t)(j * 64) * 256 + kb;
      float4 v0 = *(const float4*)p;
      float4 v1 = *(const float4*)(p + 4);
      bf16x8 u;
      u[0] = (short)f32_to_bf16(v0.x); u[1] = (short)f32_to_bf16(v0.y);
      u[2] = (short)f32_to_bf16(v0.z); u[3] = (short)f32_to_bf16(v0.w);
      u[4] = (short)f32_to_bf16(v1.x); u[5] = (short)f32_to_bf16(v1.y);
      u[6] = (short)f32_to_bf16(v1.z); u[7] = (short)f32_to_bf16(v1.w);
      *(bf16x8*)(&Bs[(j * 64 + srow) * 32 + sk0]) = u;
    }
    __syncthreads();

    const int r16 = lane & 15;
    const int qk  = (lane >> 4) << 3;  // k-offset 0/8/16/24
    bf16x8 af[4], bfr[4];
#pragma unroll
    for (int g = 0; g < 4; ++g)
      af[g] = *(const bf16x8*)(&As[(g * 16 + r16) * 32 + qk]);
#pragma unroll
    for (int g = 0; g < 4; ++g)
      bfr[g] = *(const bf16x8*)(&Bs[(wid * 64 + g * 16 + r16) * 32 + qk]);
#pragma unroll
    for (int rg = 0; rg < 4; ++rg)
#pragma unroll
      for (int cg = 0; cg < 4; ++cg)
        acc[rg][cg] = __builtin_amdgcn_mfma_f32_16x16x32_bf16(
            af[rg], bfr[cg], acc[rg][cg], 0, 0, 0);
    __syncthreads();
  }

  // epilogue: C/D layout col=lane&15, row=(lane>>4)*4+reg
  const int quad = lane >> 4;
  const int c16  = lane & 15;
#pragma unroll
  for (int rg = 0; rg < 4; ++rg) {
#pragma unroll
    for (int r = 0; r < 4; ++r) {
      int grow = row0 + rg * 16 + quad * 4 + r;
      if (grow >= M) continue;
#pragma unroll
      for (int cg = 0; cg < 4; ++cg) {
        int col = wid * 64 + cg * 16 + c16;
        float v = acc[rg][cg][r] + bias[col];
        if (grow == 0) v = 0.0f;  // padding row
        unsigned short hv = f32_to_bf16(v);
        if (sliced) {
          // h_s[col>>5][grow][col&31]
          h[((size_t)(col >> 5) * M + grow) * 32 + (col & 31)] = hv;
        } else {
          h[(size_t)grow * 256 + col] = hv;
        }
      }
    }
  }
}

// a2a[j] = b_from_a[a_from_b[j]]; also zeroes the 8 per-slice work cursors.
__global__ __launch_bounds__(256, 8) void gin_a2a(
    const int* __restrict__ b_from_a, const int* __restrict__ a_from_b,
    int* __restrict__ a2a, int* __restrict__ cursors, int n) {
  if (blockIdx.x == 0 && threadIdx.x < 8) cursors[threadIdx.x] = 0;
  int j = (blockIdx.x * 256 + threadIdx.x) * 4;
  if (j + 3 >= n) {
    for (; j < n; ++j) a2a[j] = b_from_a[a_from_b[j]];
    return;
  }
  i32x4 f = *(const i32x4*)(a_from_b + j);
  i32x4 r;
  r[0] = b_from_a[f[0]]; r[1] = b_from_a[f[1]];
  r[2] = b_from_a[f[2]]; r[3] = b_from_a[f[3]];
  *(i32x4*)(a2a + j) = r;
}

// XCD-sliced gather v2. Slice chosen from the PHYSICAL XCD id (HW_REG_XCC_ID),
// so each XCD's 4MB L2 serves its own 3.2MB h-slice regardless of how blocks
// are dispatched. Work distributed via 8 device-scope atomic cursors: blocks
// drain their own slice, then steal from the others (correct under any
// block->XCD mapping). Output uses PLAIN stores so the TCC merges the 4x32B
// per-atom segments into full lines (round-4's nt stores caused 6.3x write
// amplification and flushed L2+L3).
// Wave layout: 16 atoms/group, 4 lanes per atom, 16B (8 cols) per lane.
__global__ __launch_bounds__(256, 8) void gin_gather_sliced(
    const unsigned short* __restrict__ hs, const int* __restrict__ a2a,
    int* __restrict__ cursors, float* __restrict__ out, int M) {
  const int lane = threadIdx.x & 63;
  const int a    = lane >> 2;             // atom-in-group 0..15
  const int sub  = lane & 3;              // 16B sub-chunk of the 64B slice row
  const int ngroups = (M + 15) >> 4;      // 3125 for M=50000

  unsigned int xcc;
  asm("s_getreg_b32 %0, hwreg(HW_REG_XCC_ID)" : "=s"(xcc));
  xcc &= 7;

  for (int ss = 0; ss < 8; ++ss) {
    const int s = (xcc + ss) & 7;
    const unsigned short* __restrict__ hsl = hs + (size_t)s * M * 32;
    for (;;) {
      int g;
      if (lane == 0) g = atomicAdd(&cursors[s], 1);
      g = __shfl(g, 0, 64);
      if (g >= ngroups) break;

      const int i0 = g * 16;
      int idx = i0 * 16 + lane * 4;       // 256 neighbor ids for this group
      int lim = M * 16 - 4;
      if (idx > lim) idx = lim;
      i32x4 ids = __builtin_nontemporal_load((const i32x4*)(a2a + idx));

      float s0 = 0, s1 = 0, s2 = 0, s3 = 0, s4 = 0, s5 = 0, s6 = 0, s7 = 0;
#pragma unroll
      for (int k = 0; k < 16; ++k) {
        // flat = a*16+k -> source lane a*4 + (k>>2), element k&3 (compile-time)
        int id = __shfl(ids[k & 3], a * 4 + (k >> 2), 64);
        u32x4 v = *(const u32x4*)(hsl + (size_t)id * 32 + sub * 8);
        s0 += bf16lo_to_f32(v[0]); s1 += bf16hi_to_f32(v[0]);
        s2 += bf16lo_to_f32(v[1]); s3 += bf16hi_to_f32(v[1]);
        s4 += bf16lo_to_f32(v[2]); s5 += bf16hi_to_f32(v[2]);
        s6 += bf16lo_to_f32(v[3]); s7 += bf16hi_to_f32(v[3]);
      }
      // self term (h already contains bias; row 0 zeroed in GEMM)
      const int self  = i0 + a;
      const int selfc = self < M ? self : M - 1;
      u32x4 v = *(const u32x4*)(hsl + (size_t)selfc * 32 + sub * 8);
      s0 += bf16lo_to_f32(v[0]); s1 += bf16hi_to_f32(v[0]);
      s2 += bf16lo_to_f32(v[1]); s3 += bf16hi_to_f32(v[1]);
      s4 += bf16lo_to_f32(v[2]); s5 += bf16hi_to_f32(v[2]);
      s6 += bf16lo_to_f32(v[3]); s7 += bf16hi_to_f32(v[3]);

      if (self < M) {
        f32x4 r0, r1;
        r0[0] = fmaxf(s0, 0.0f); r0[1] = fmaxf(s1, 0.0f);
        r0[2] = fmaxf(s2, 0.0f); r0[3] = fmaxf(s3, 0.0f);
        r1[0] = fmaxf(s4, 0.0f); r1[1] = fmaxf(s5, 0.0f);
        r1[2] = fmaxf(s6, 0.0f); r1[3] = fmaxf(s7, 0.0f);
        float* op = out + (size_t)self * 256 + s * 32 + sub * 8;
        *(f32x4*)op = r0;
        *(f32x4*)(op + 4) = r1;
      }
    }
  }
}

// Fallback gather (row-major h), used if workspace can't hold h + a2a + cursors.
__global__ __launch_bounds__(256, 4) void gin_gather(
    const unsigned short* __restrict__ h, const int* __restrict__ b_from_a,
    const int* __restrict__ a_from_b, float* __restrict__ out, int N) {
  const int tid  = threadIdx.x;
  const int wid  = tid >> 6;
  const int lane = tid & 63;
  const int half = lane >> 5;
  const int l32  = lane & 31;
  const int i0   = blockIdx.x * 8 + wid * 2;
  if (i0 >= N) return;
  const int row  = i0 + half;
  const int rowc = (row < N) ? row : (N - 1);

  int src = 0;
  if (lane < 32) {
    int idx = i0 * 16 + lane;
    int lim = N * 16 - 1;
    if (idx > lim) idx = lim;
    src = b_from_a[a_from_b[idx]];
  }

  const int c0 = l32 * 8;
  uint4 u = *(const uint4*)(h + (size_t)rowc * 256 + c0);
  float a0 = bf16lo_to_f32(u.x), a1 = bf16hi_to_f32(u.x);
  float a2 = bf16lo_to_f32(u.y), a3 = bf16hi_to_f32(u.y);
  float a4 = bf16lo_to_f32(u.z), a5 = bf16hi_to_f32(u.z);
  float a6 = bf16lo_to_f32(u.w), a7 = bf16hi_to_f32(u.w);

#pragma unroll
  for (int k = 0; k < 16; ++k) {
    int s = __shfl(src, half * 16 + k, 64);
    uint4 v = *(const uint4*)(h + (size_t)s * 256 + c0);
    a0 += bf16lo_to_f32(v.x); a1 += bf16hi_to_f32(v.x);
    a2 += bf16lo_to_f32(v.y); a3 += bf16hi_to_f32(v.y);
    a4 += bf16lo_to_f32(v.z); a5 += bf16hi_to_f32(v.z);
    a6 += bf16lo_to_f32(v.w); a7 += bf16hi_to_f32(v.w);
  }

  if (row < N) {
    f32x4 r0, r1;
    r0[0] = fmaxf(a0, 0.0f); r0[1] = fmaxf(a1, 0.0f);
    r0[2] = fmaxf(a2, 0.0f); r0[3] = fmaxf(a3, 0.0f);
    r1[0] = fmaxf(a4, 0.0f); r1[1] = fmaxf(a5, 0.0f);
    r1[2] = fmaxf(a6, 0.0f); r1[3] = fmaxf(a7, 0.0f);
    float* op = out + (size_t)row * 256 + c0;
    *(f32x4*)op = r0;
    *(f32x4*)(op + 4) = r1;
  }
}

extern "C" void kernel_launch(void* const* d_in, const int* in_sizes, int n_in,
                              void* d_out, int out_size, void* d_ws, size_t ws_size,
                              hipStream_t stream) {
  const float* x        = (const float*)d_in[0];
  const float* W        = (const float*)d_in[1];
  const float* b        = (const float*)d_in[2];
  const int*   b_from_a = (const int*)d_in[3];
  const int*   a_from_b = (const int*)d_in[4];
  float*       out      = (float*)d_out;
  const int M = in_sizes[0] / 256;  // 50000 atoms

  unsigned short* h = (unsigned short*)d_ws;              // bf16 h, 25.6 MB
  const size_t h_bytes   = (size_t)M * 256 * sizeof(unsigned short);
  const size_t a2a_bytes = (size_t)M * 16 * sizeof(int);  // 3.2 MB
  const size_t cur_bytes = 8 * sizeof(int);

  if (ws_size >= h_bytes + a2a_bytes + cur_bytes) {
    int* a2a     = (int*)((char*)d_ws + h_bytes);
    int* cursors = (int*)((char*)d_ws + h_bytes + a2a_bytes);
    const int n = M * 16;
    gin_a2a<<<(n / 4 + 255) / 256, 256, 0, stream>>>(b_from_a, a_from_b, a2a,
                                                     cursors, n);
    gin_gemm<<<(M + 63) / 64, 256, 0, stream>>>(x, W, b, h, M, 1);
    gin_gather_sliced<<<2048, 256, 0, stream>>>(h, a2a, cursors, out, M);
  } else {
    gin_gemm<<<(M + 63) / 64, 256, 0, stream>>>(x, W, b, h, M, 0);
    gin_gather<<<(M + 7) / 8, 256, 0, stream>>>(h, b_from_a, a_from_b, out, M);
  }
}

// Round 6
// 238.019 us; speedup vs baseline: 5.0430x; 5.0430x over previous
//
#include <hip/hip_runtime.h>

typedef short bf16x8 __attribute__((ext_vector_type(8)));
typedef float f32x4  __attribute__((ext_vector_type(4)));

__device__ __forceinline__ unsigned short f32_to_bf16(float f) {
  union { float f; unsigned int u; } v; v.f = f;
  unsigned int u = v.u;
  u += 0x7fffu + ((u >> 16) & 1u);   // round-to-nearest-even
  return (unsigned short)(u >> 16);
}
__device__ __forceinline__ float bf16lo_to_f32(unsigned int u) {
  union { unsigned int u; float f; } v; v.u = u << 16; return v.f;
}
__device__ __forceinline__ float bf16hi_to_f32(unsigned int u) {
  union { unsigned int u; float f; } v; v.u = u & 0xffff0000u; return v.f;
}

__device__ __forceinline__ bf16x8 cvt_f32x8_bf16(float4 v0, float4 v1) {
  bf16x8 u;
  u[0] = (short)f32_to_bf16(v0.x); u[1] = (short)f32_to_bf16(v0.y);
  u[2] = (short)f32_to_bf16(v0.z); u[3] = (short)f32_to_bf16(v0.w);
  u[4] = (short)f32_to_bf16(v1.x); u[5] = (short)f32_to_bf16(v1.y);
  u[6] = (short)f32_to_bf16(v1.z); u[7] = (short)f32_to_bf16(v1.w);
  return u;
}

// h = x @ W.T + b, h[0,:] = 0, stored row-major bf16.
// LDS-free, barrier-free GEMM: fragments are loaded DIRECTLY from global.
// Per K-tile a wave's A-read is 16 rows x 64B contiguous (4 lanes/row) --
// line-granular; all 4 waves read the same A rows (L1 broadcast) and all
// blocks read the same W (256KB, L2-resident). f32->bf16 cvt runs on the
// VALU pipe and overlaps MFMA + the HBM stream; no __syncthreads at all.
__global__ __launch_bounds__(256, 3) void gin_gemm(
    const float* __restrict__ x, const float* __restrict__ W,
    const float* __restrict__ bias, unsigned short* __restrict__ h, int M) {
  const int tid  = threadIdx.x;
  const int wid  = tid >> 6;
  const int lane = tid & 63;
  const int row0 = blockIdx.x * 64;
  const int r16  = lane & 15;
  const int qk   = (lane >> 4) << 3;   // k-elem offset 0/8/16/24 within K-tile

  f32x4 acc[4][4] = {};  // [row-group][col-group], 64 VGPRs

  const float* aP[4];
  const float* bP[4];
#pragma unroll
  for (int g = 0; g < 4; ++g) {
    int ar = row0 + g * 16 + r16;
    if (ar >= M) ar = M - 1;           // clamp; write guarded in epilogue
    aP[g] = x + (size_t)ar * 256 + qk;
    bP[g] = W + (size_t)(wid * 64 + g * 16 + r16) * 256 + qk;
  }

  for (int kt = 0; kt < 8; ++kt) {
    const int kb = kt * 32;
    bf16x8 af[4], bfr[4];
#pragma unroll
    for (int g = 0; g < 4; ++g) {
      float4 v0 = *(const float4*)(aP[g] + kb);
      float4 v1 = *(const float4*)(aP[g] + kb + 4);
      af[g] = cvt_f32x8_bf16(v0, v1);
    }
#pragma unroll
    for (int g = 0; g < 4; ++g) {
      float4 v0 = *(const float4*)(bP[g] + kb);
      float4 v1 = *(const float4*)(bP[g] + kb + 4);
      bfr[g] = cvt_f32x8_bf16(v0, v1);
    }
#pragma unroll
    for (int rg = 0; rg < 4; ++rg)
#pragma unroll
      for (int cg = 0; cg < 4; ++cg)
        acc[rg][cg] = __builtin_amdgcn_mfma_f32_16x16x32_bf16(
            af[rg], bfr[cg], acc[rg][cg], 0, 0, 0);
  }

  // epilogue: C/D layout col=lane&15, row=(lane>>4)*4+reg
  const int quad = lane >> 4;
  const int c16  = lane & 15;
#pragma unroll
  for (int rg = 0; rg < 4; ++rg) {
#pragma unroll
    for (int r = 0; r < 4; ++r) {
      int grow = row0 + rg * 16 + quad * 4 + r;
      if (grow >= M) continue;
#pragma unroll
      for (int cg = 0; cg < 4; ++cg) {
        int col = wid * 64 + cg * 16 + c16;
        float v = acc[rg][cg][r] + bias[col];
        if (grow == 0) v = 0.0f;  // padding row
        h[(size_t)grow * 256 + col] = f32_to_bf16(v);
      }
    }
  }
}

// out[i] = relu(h[i] + sum_k h[b_from_a[a_from_b[i,k]]]).
// Round-3 verified version (69us, L3-resident): one wave serves TWO atoms
// (lane halves); uint4 16B loads -> 1KB per gather instruction across two
// rows. Index loads coalesced over 32 lanes. nt-stores (2KB contiguous per
// wave) keep h resident in L2/L3.
__global__ __launch_bounds__(256, 4) void gin_gather(
    const unsigned short* __restrict__ h, const int* __restrict__ b_from_a,
    const int* __restrict__ a_from_b, float* __restrict__ out, int N) {
  const int tid  = threadIdx.x;
  const int wid  = tid >> 6;
  const int lane = tid & 63;
  const int half = lane >> 5;          // 0: atom i0, 1: atom i0+1
  const int l32  = lane & 31;
  const int i0   = blockIdx.x * 8 + wid * 2;
  if (i0 >= N) return;
  const int row  = i0 + half;
  const int rowc = (row < N) ? row : (N - 1);   // clamp; tail discarded

  // Both atoms' 32 bond ids in one coalesced 128B load across lanes 0..31.
  int src = 0;
  if (lane < 32) {
    int idx = i0 * 16 + lane;
    int lim = N * 16 - 1;
    if (idx > lim) idx = lim;
    src = b_from_a[a_from_b[idx]];
  }

  const int c0 = l32 * 8;              // 8 bf16 cols per lane
  uint4 u = *(const uint4*)(h + (size_t)rowc * 256 + c0);
  float a0 = bf16lo_to_f32(u.x), a1 = bf16hi_to_f32(u.x);
  float a2 = bf16lo_to_f32(u.y), a3 = bf16hi_to_f32(u.y);
  float a4 = bf16lo_to_f32(u.z), a5 = bf16hi_to_f32(u.z);
  float a6 = bf16lo_to_f32(u.w), a7 = bf16hi_to_f32(u.w);

#pragma unroll
  for (int k = 0; k < 16; ++k) {
    int s = __shfl(src, half * 16 + k, 64);   // wave-half-uniform source row
    uint4 v = *(const uint4*)(h + (size_t)s * 256 + c0);
    a0 += bf16lo_to_f32(v.x); a1 += bf16hi_to_f32(v.x);
    a2 += bf16lo_to_f32(v.y); a3 += bf16hi_to_f32(v.y);
    a4 += bf16lo_to_f32(v.z); a5 += bf16hi_to_f32(v.z);
    a6 += bf16lo_to_f32(v.w); a7 += bf16hi_to_f32(v.w);
  }

  if (row < N) {
    f32x4 r0, r1;
    r0[0] = fmaxf(a0, 0.0f); r0[1] = fmaxf(a1, 0.0f);
    r0[2] = fmaxf(a2, 0.0f); r0[3] = fmaxf(a3, 0.0f);
    r1[0] = fmaxf(a4, 0.0f); r1[1] = fmaxf(a5, 0.0f);
    r1[2] = fmaxf(a6, 0.0f); r1[3] = fmaxf(a7, 0.0f);
    float* op = out + (size_t)row * 256 + c0;
    __builtin_nontemporal_store(r0, (f32x4*)op);
    __builtin_nontemporal_store(r1, (f32x4*)(op + 4));
  }
}

extern "C" void kernel_launch(void* const* d_in, const int* in_sizes, int n_in,
                              void* d_out, int out_size, void* d_ws, size_t ws_size,
                              hipStream_t stream) {
  const float* x        = (const float*)d_in[0];
  const float* W        = (const float*)d_in[1];
  const float* b        = (const float*)d_in[2];
  const int*   b_from_a = (const int*)d_in[3];
  const int*   a_from_b = (const int*)d_in[4];
  float*       out      = (float*)d_out;
  const int M = in_sizes[0] / 256;  // 50000 atoms

  unsigned short* h = (unsigned short*)d_ws;  // bf16 h, 25.6 MB

  gin_gemm<<<(M + 63) / 64, 256, 0, stream>>>(x, W, b, h, M);
  gin_gather<<<(M + 7) / 8, 256, 0, stream>>>(h, b_from_a, a_from_b, out, M);
}

// Round 7
// 193.994 us; speedup vs baseline: 6.1875x; 1.2269x over previous
//
#include <hip/hip_runtime.h>

typedef short bf16x4 __attribute__((ext_vector_type(4)));
typedef short bf16x8 __attribute__((ext_vector_type(8)));
typedef float f32x4  __attribute__((ext_vector_type(4)));

__device__ __forceinline__ unsigned short f32_to_bf16(float f) {
  union { float f; unsigned int u; } v; v.f = f;
  unsigned int u = v.u;
  u += 0x7fffu + ((u >> 16) & 1u);   // round-to-nearest-even
  return (unsigned short)(u >> 16);
}
__device__ __forceinline__ float bf16lo_to_f32(unsigned int u) {
  union { unsigned int u; float f; } v; v.u = u << 16; return v.f;
}
__device__ __forceinline__ float bf16hi_to_f32(unsigned int u) {
  union { unsigned int u; float f; } v; v.u = u & 0xffff0000u; return v.f;
}

// h = x @ W.T + b, h[0,:] = 0, stored row-major bf16.
// Round-3 LDS structure, upgraded: 512 threads (8 waves; wave w owns 32 cols)
// -> 3 blocks/CU = 24 waves/CU (was 12), halved staging work per thread.
// LDS rows padded to 40 shorts (80B = 20 banks): fragment reads walk rows at
// 80B stride -> <=2-way bank aliasing (free) instead of 8-way at 64B stride.
#define LDP 40
__global__ __launch_bounds__(512, 4) void gin_gemm(
    const float* __restrict__ x, const float* __restrict__ W,
    const float* __restrict__ bias, unsigned short* __restrict__ h, int M) {
  __shared__ __align__(16) unsigned short As[64 * LDP];    // 5.1 KB
  __shared__ __align__(16) unsigned short Bs[256 * LDP];   // 20.5 KB

  const int tid  = threadIdx.x;
  const int wid  = tid >> 6;          // 0..7
  const int lane = tid & 63;
  const int row0 = blockIdx.x * 64;

  f32x4 acc[4][2] = {};  // [row-group][col-group], 32 VGPRs

  // A staging: thread covers 4 contiguous k's of one row (64x32 tile)
  const int srowA = tid >> 3;         // 0..63
  const int skA   = (tid & 7) << 2;   // 0,4,..,28
  int agrow = row0 + srowA;
  if (agrow >= M) agrow = M - 1;      // clamp; results discarded in epilogue
  const float* aRow = x + (size_t)agrow * 256 + skA;
  // B staging: thread covers 8 contiguous k's of rows {srowB, srowB+128}
  const int srowB = tid >> 2;         // 0..127
  const int skB   = (tid & 3) << 3;   // 0,8,16,24
  const float* bRow = W + (size_t)srowB * 256 + skB;

  for (int kt = 0; kt < 8; ++kt) {
    const int kb = kt * 32;
    // stage A: 64x32 f32 -> bf16
    {
      float4 v = *(const float4*)(aRow + kb);
      bf16x4 u;
      u[0] = (short)f32_to_bf16(v.x); u[1] = (short)f32_to_bf16(v.y);
      u[2] = (short)f32_to_bf16(v.z); u[3] = (short)f32_to_bf16(v.w);
      *(bf16x4*)(&As[srowA * LDP + skA]) = u;
    }
    // stage B: 256x32 (W rows = output cols), 2 rows per thread
#pragma unroll
    for (int j = 0; j < 2; ++j) {
      const float* p = bRow + (size_t)(j * 128) * 256 + kb;
      float4 v0 = *(const float4*)p;
      float4 v1 = *(const float4*)(p + 4);
      bf16x8 u;
      u[0] = (short)f32_to_bf16(v0.x); u[1] = (short)f32_to_bf16(v0.y);
      u[2] = (short)f32_to_bf16(v0.z); u[3] = (short)f32_to_bf16(v0.w);
      u[4] = (short)f32_to_bf16(v1.x); u[5] = (short)f32_to_bf16(v1.y);
      u[6] = (short)f32_to_bf16(v1.z); u[7] = (short)f32_to_bf16(v1.w);
      *(bf16x8*)(&Bs[(j * 128 + srowB) * LDP + skB]) = u;
    }
    __syncthreads();

    const int r16 = lane & 15;
    const int qk  = (lane >> 4) << 3;  // k-offset 0/8/16/24
    bf16x8 af[4], bfr[2];
#pragma unroll
    for (int g = 0; g < 4; ++g)
      af[g] = *(const bf16x8*)(&As[(g * 16 + r16) * LDP + qk]);
#pragma unroll
    for (int g = 0; g < 2; ++g)
      bfr[g] = *(const bf16x8*)(&Bs[(wid * 32 + g * 16 + r16) * LDP + qk]);
#pragma unroll
    for (int rg = 0; rg < 4; ++rg)
#pragma unroll
      for (int cg = 0; cg < 2; ++cg)
        acc[rg][cg] = __builtin_amdgcn_mfma_f32_16x16x32_bf16(
            af[rg], bfr[cg], acc[rg][cg], 0, 0, 0);
    __syncthreads();
  }

  // epilogue: C/D layout col=lane&15, row=(lane>>4)*4+reg
  const int quad = lane >> 4;
  const int c16  = lane & 15;
#pragma unroll
  for (int rg = 0; rg < 4; ++rg) {
#pragma unroll
    for (int r = 0; r < 4; ++r) {
      int grow = row0 + rg * 16 + quad * 4 + r;
      if (grow >= M) continue;
#pragma unroll
      for (int cg = 0; cg < 2; ++cg) {
        int col = wid * 32 + cg * 16 + c16;
        float v = acc[rg][cg][r] + bias[col];
        if (grow == 0) v = 0.0f;  // padding row
        h[(size_t)grow * 256 + col] = f32_to_bf16(v);
      }
    }
  }
}

// out[i] = relu(h[i] + sum_k h[b_from_a[a_from_b[i,k]]]).
// Round-3 verified version (69us, L3-BW-bound): one wave serves TWO atoms
// (lane halves); uint4 16B loads -> 1KB per gather instruction across two
// rows. Index loads coalesced over 32 lanes. nt-stores (2KB contiguous per
// wave) keep h resident in L2/L3.
__global__ __launch_bounds__(256, 4) void gin_gather(
    const unsigned short* __restrict__ h, const int* __restrict__ b_from_a,
    const int* __restrict__ a_from_b, float* __restrict__ out, int N) {
  const int tid  = threadIdx.x;
  const int wid  = tid >> 6;
  const int lane = tid & 63;
  const int half = lane >> 5;          // 0: atom i0, 1: atom i0+1
  const int l32  = lane & 31;
  const int i0   = blockIdx.x * 8 + wid * 2;
  if (i0 >= N) return;
  const int row  = i0 + half;
  const int rowc = (row < N) ? row : (N - 1);   // clamp; tail discarded

  // Both atoms' 32 bond ids in one coalesced 128B load across lanes 0..31.
  int src = 0;
  if (lane < 32) {
    int idx = i0 * 16 + lane;
    int lim = N * 16 - 1;
    if (idx > lim) idx = lim;
    src = b_from_a[a_from_b[idx]];
  }

  const int c0 = l32 * 8;              // 8 bf16 cols per lane
  uint4 u = *(const uint4*)(h + (size_t)rowc * 256 + c0);
  float a0 = bf16lo_to_f32(u.x), a1 = bf16hi_to_f32(u.x);
  float a2 = bf16lo_to_f32(u.y), a3 = bf16hi_to_f32(u.y);
  float a4 = bf16lo_to_f32(u.z), a5 = bf16hi_to_f32(u.z);
  float a6 = bf16lo_to_f32(u.w), a7 = bf16hi_to_f32(u.w);

#pragma unroll
  for (int k = 0; k < 16; ++k) {
    int s = __shfl(src, half * 16 + k, 64);   // wave-half-uniform source row
    uint4 v = *(const uint4*)(h + (size_t)s * 256 + c0);
    a0 += bf16lo_to_f32(v.x); a1 += bf16hi_to_f32(v.x);
    a2 += bf16lo_to_f32(v.y); a3 += bf16hi_to_f32(v.y);
    a4 += bf16lo_to_f32(v.z); a5 += bf16hi_to_f32(v.z);
    a6 += bf16lo_to_f32(v.w); a7 += bf16hi_to_f32(v.w);
  }

  if (row < N) {
    f32x4 r0, r1;
    r0[0] = fmaxf(a0, 0.0f); r0[1] = fmaxf(a1, 0.0f);
    r0[2] = fmaxf(a2, 0.0f); r0[3] = fmaxf(a3, 0.0f);
    r1[0] = fmaxf(a4, 0.0f); r1[1] = fmaxf(a5, 0.0f);
    r1[2] = fmaxf(a6, 0.0f); r1[3] = fmaxf(a7, 0.0f);
    float* op = out + (size_t)row * 256 + c0;
    __builtin_nontemporal_store(r0, (f32x4*)op);
    __builtin_nontemporal_store(r1, (f32x4*)(op + 4));
  }
}

extern "C" void kernel_launch(void* const* d_in, const int* in_sizes, int n_in,
                              void* d_out, int out_size, void* d_ws, size_t ws_size,
                              hipStream_t stream) {
  const float* x        = (const float*)d_in[0];
  const float* W        = (const float*)d_in[1];
  const float* b        = (const float*)d_in[2];
  const int*   b_from_a = (const int*)d_in[3];
  const int*   a_from_b = (const int*)d_in[4];
  float*       out      = (float*)d_out;
  const int M = in_sizes[0] / 256;  // 50000 atoms

  unsigned short* h = (unsigned short*)d_ws;  // bf16 h, 25.6 MB

  gin_gemm<<<(M + 63) / 64, 512, 0, stream>>>(x, W, b, h, M);
  gin_gather<<<(M + 7) / 8, 256, 0, stream>>>(h, b_from_a, a_from_b, out, M);
}

// Round 8
// 193.984 us; speedup vs baseline: 6.1878x; 1.0001x over previous
//
#include <hip/hip_runtime.h>

typedef short bf16x4 __attribute__((ext_vector_type(4)));
typedef short bf16x8 __attribute__((ext_vector_type(8)));
typedef float f32x4  __attribute__((ext_vector_type(4)));

__device__ __forceinline__ unsigned short f32_to_bf16(float f) {
  union { float f; unsigned int u; } v; v.f = f;
  unsigned int u = v.u;
  u += 0x7fffu + ((u >> 16) & 1u);   // round-to-nearest-even
  return (unsigned short)(u >> 16);
}
__device__ __forceinline__ float bf16lo_to_f32(unsigned int u) {
  union { unsigned int u; float f; } v; v.u = u << 16; return v.f;
}
__device__ __forceinline__ float bf16hi_to_f32(unsigned int u) {
  union { unsigned int u; float f; } v; v.u = u & 0xffff0000u; return v.f;
}
__device__ __forceinline__ bf16x4 cvt4(float4 v) {
  bf16x4 u;
  u[0] = (short)f32_to_bf16(v.x); u[1] = (short)f32_to_bf16(v.y);
  u[2] = (short)f32_to_bf16(v.z); u[3] = (short)f32_to_bf16(v.w);
  return u;
}
__device__ __forceinline__ bf16x8 cvt8(float4 v0, float4 v1) {
  bf16x8 u;
  u[0] = (short)f32_to_bf16(v0.x); u[1] = (short)f32_to_bf16(v0.y);
  u[2] = (short)f32_to_bf16(v0.z); u[3] = (short)f32_to_bf16(v0.w);
  u[4] = (short)f32_to_bf16(v1.x); u[5] = (short)f32_to_bf16(v1.y);
  u[6] = (short)f32_to_bf16(v1.z); u[7] = (short)f32_to_bf16(v1.w);
  return u;
}

// h = x @ W.T + b, h[0,:] = 0, stored row-major bf16.
// r7 structure (512 thr, 8 waves x 32 cols, LDP=40 pad) + DOUBLE-BUFFERED
// software pipeline: step kt issues kt+1's global loads BEFORE the MFMAs,
// converts+ds_writes them AFTER, into buf[1-(kt&1)]; ONE barrier per step.
// This removes the per-step vmcnt(0) drain (~700cy HBM latency x 8 steps)
// that serialized the r7 version.
#define LDP 40
__global__ __launch_bounds__(512, 4) void gin_gemm(
    const float* __restrict__ x, const float* __restrict__ W,
    const float* __restrict__ bias, unsigned short* __restrict__ h, int M) {
  __shared__ __align__(16) unsigned short As[2][64 * LDP];    // 2x 5.1 KB
  __shared__ __align__(16) unsigned short Bs[2][256 * LDP];   // 2x 20.5 KB

  const int tid  = threadIdx.x;
  const int wid  = tid >> 6;          // 0..7
  const int lane = tid & 63;
  const int row0 = blockIdx.x * 64;
  const int r16  = lane & 15;
  const int qk   = (lane >> 4) << 3;  // k-offset 0/8/16/24

  f32x4 acc[4][2] = {};  // [row-group][col-group]

  // A staging: thread covers 4 contiguous k's of one row (64x32 tile)
  const int srowA = tid >> 3;         // 0..63
  const int skA   = (tid & 7) << 2;   // 0,4,..,28
  int agrow = row0 + srowA;
  if (agrow >= M) agrow = M - 1;      // clamp; results discarded in epilogue
  const float* aRow = x + (size_t)agrow * 256 + skA;
  // B staging: thread covers 8 contiguous k's of rows {srowB, srowB+128}
  const int srowB = tid >> 2;         // 0..127
  const int skB   = (tid & 3) << 3;   // 0,8,16,24
  const float* bRow = W + (size_t)srowB * 256 + skB;

  // ---- prologue: stage K-tile 0 into buf0 ----
  {
    float4 av  = *(const float4*)(aRow);
    float4 b00 = *(const float4*)(bRow);
    float4 b01 = *(const float4*)(bRow + 4);
    float4 b10 = *(const float4*)(bRow + (size_t)128 * 256);
    float4 b11 = *(const float4*)(bRow + (size_t)128 * 256 + 4);
    *(bf16x4*)(&As[0][srowA * LDP + skA]) = cvt4(av);
    *(bf16x8*)(&Bs[0][srowB * LDP + skB]) = cvt8(b00, b01);
    *(bf16x8*)(&Bs[0][(128 + srowB) * LDP + skB]) = cvt8(b10, b11);
  }
  __syncthreads();

#pragma unroll
  for (int kt = 0; kt < 8; ++kt) {
    const int cur = kt & 1;
    // issue NEXT tile's global loads first (fire-and-forget into regs)
    float4 nav, nb00, nb01, nb10, nb11;
    if (kt < 7) {
      const int kb = (kt + 1) * 32;
      nav  = *(const float4*)(aRow + kb);
      nb00 = *(const float4*)(bRow + kb);
      nb01 = *(const float4*)(bRow + kb + 4);
      nb10 = *(const float4*)(bRow + (size_t)128 * 256 + kb);
      nb11 = *(const float4*)(bRow + (size_t)128 * 256 + kb + 4);
    }
    // compute current tile from buf[cur]
    bf16x8 af[4], bfr[2];
#pragma unroll
    for (int g = 0; g < 4; ++g)
      af[g] = *(const bf16x8*)(&As[cur][(g * 16 + r16) * LDP + qk]);
#pragma unroll
    for (int g = 0; g < 2; ++g)
      bfr[g] = *(const bf16x8*)(&Bs[cur][(wid * 32 + g * 16 + r16) * LDP + qk]);
#pragma unroll
    for (int rg = 0; rg < 4; ++rg)
#pragma unroll
      for (int cg = 0; cg < 2; ++cg)
        acc[rg][cg] = __builtin_amdgcn_mfma_f32_16x16x32_bf16(
            af[rg], bfr[cg], acc[rg][cg], 0, 0, 0);
    // convert + stage next tile into buf[cur^1]; one barrier per step.
    // Safe: buf[cur^1] was last read in step kt-1, all waves passed that
    // step's barrier before any ds_write here.
    if (kt < 7) {
      *(bf16x4*)(&As[cur ^ 1][srowA * LDP + skA]) = cvt4(nav);
      *(bf16x8*)(&Bs[cur ^ 1][srowB * LDP + skB]) = cvt8(nb00, nb01);
      *(bf16x8*)(&Bs[cur ^ 1][(128 + srowB) * LDP + skB]) = cvt8(nb10, nb11);
      __syncthreads();
    }
  }

  // epilogue: C/D layout col=lane&15, row=(lane>>4)*4+reg
  const int quad = lane >> 4;
  const int c16  = lane & 15;
#pragma unroll
  for (int rg = 0; rg < 4; ++rg) {
#pragma unroll
    for (int r = 0; r < 4; ++r) {
      int grow = row0 + rg * 16 + quad * 4 + r;
      if (grow >= M) continue;
#pragma unroll
      for (int cg = 0; cg < 2; ++cg) {
        int col = wid * 32 + cg * 16 + c16;
        float v = acc[rg][cg][r] + bias[col];
        if (grow == 0) v = 0.0f;  // padding row
        h[(size_t)grow * 256 + col] = f32_to_bf16(v);
      }
    }
  }
}

// out[i] = relu(h[i] + sum_k h[b_from_a[a_from_b[i,k]]]).
// Round-3 verified version (69us): one wave serves TWO atoms (lane halves);
// uint4 16B loads -> 1KB per gather instruction across two rows. Index loads
// coalesced over 32 lanes. nt-stores (2KB contiguous per wave).
__global__ __launch_bounds__(256, 4) void gin_gather(
    const unsigned short* __restrict__ h, const int* __restrict__ b_from_a,
    const int* __restrict__ a_from_b, float* __restrict__ out, int N) {
  const int tid  = threadIdx.x;
  const int wid  = tid >> 6;
  const int lane = tid & 63;
  const int half = lane >> 5;          // 0: atom i0, 1: atom i0+1
  const int l32  = lane & 31;
  const int i0   = blockIdx.x * 8 + wid * 2;
  if (i0 >= N) return;
  const int row  = i0 + half;
  const int rowc = (row < N) ? row : (N - 1);   // clamp; tail discarded

  // Both atoms' 32 bond ids in one coalesced 128B load across lanes 0..31.
  int src = 0;
  if (lane < 32) {
    int idx = i0 * 16 + lane;
    int lim = N * 16 - 1;
    if (idx > lim) idx = lim;
    src = b_from_a[a_from_b[idx]];
  }

  const int c0 = l32 * 8;              // 8 bf16 cols per lane
  uint4 u = *(const uint4*)(h + (size_t)rowc * 256 + c0);
  float a0 = bf16lo_to_f32(u.x), a1 = bf16hi_to_f32(u.x);
  float a2 = bf16lo_to_f32(u.y), a3 = bf16hi_to_f32(u.y);
  float a4 = bf16lo_to_f32(u.z), a5 = bf16hi_to_f32(u.z);
  float a6 = bf16lo_to_f32(u.w), a7 = bf16hi_to_f32(u.w);

#pragma unroll
  for (int k = 0; k < 16; ++k) {
    int s = __shfl(src, half * 16 + k, 64);   // wave-half-uniform source row
    uint4 v = *(const uint4*)(h + (size_t)s * 256 + c0);
    a0 += bf16lo_to_f32(v.x); a1 += bf16hi_to_f32(v.x);
    a2 += bf16lo_to_f32(v.y); a3 += bf16hi_to_f32(v.y);
    a4 += bf16lo_to_f32(v.z); a5 += bf16hi_to_f32(v.z);
    a6 += bf16lo_to_f32(v.w); a7 += bf16hi_to_f32(v.w);
  }

  if (row < N) {
    f32x4 r0, r1;
    r0[0] = fmaxf(a0, 0.0f); r0[1] = fmaxf(a1, 0.0f);
    r0[2] = fmaxf(a2, 0.0f); r0[3] = fmaxf(a3, 0.0f);
    r1[0] = fmaxf(a4, 0.0f); r1[1] = fmaxf(a5, 0.0f);
    r1[2] = fmaxf(a6, 0.0f); r1[3] = fmaxf(a7, 0.0f);
    float* op = out + (size_t)row * 256 + c0;
    __builtin_nontemporal_store(r0, (f32x4*)op);
    __builtin_nontemporal_store(r1, (f32x4*)(op + 4));
  }
}

extern "C" void kernel_launch(void* const* d_in, const int* in_sizes, int n_in,
                              void* d_out, int out_size, void* d_ws, size_t ws_size,
                              hipStream_t stream) {
  const float* x        = (const float*)d_in[0];
  const float* W        = (const float*)d_in[1];
  const float* b        = (const float*)d_in[2];
  const int*   b_from_a = (const int*)d_in[3];
  const int*   a_from_b = (const int*)d_in[4];
  float*       out      = (float*)d_out;
  const int M = in_sizes[0] / 256;  // 50000 atoms

  unsigned short* h = (unsigned short*)d_ws;  // bf16 h, 25.6 MB

  gin_gemm<<<(M + 63) / 64, 512, 0, stream>>>(x, W, b, h, M);
  gin_gather<<<(M + 7) / 8, 256, 0, stream>>>(h, b_from_a, a_from_b, out, M);
}